// Round 7
// baseline (437.066 us; speedup 1.0000x reference)
//
#include <hip/hip_runtime.h>

// MHA forward, MI355X gfx950. B=2 S=2048 H=1024 NH=16 HD=64, fp32 I/O.
// R7: split-K(4) attn (4 blocks/CU, 32 waves/CU), XOR-algebra fragment
//     offsets (off ^ (ks<<5)), double-buffered prefetch GEMMs (T3-min).

#define BB   2
#define SS   2048
#define HH   1024
#define NHH  16
#define HDD  64

#define LOG2E 1.4426950408889634f
#define C1    (0.125f * LOG2E)   // qk scale folded into log2 domain

typedef _Float16 h8 __attribute__((ext_vector_type(8)));
typedef float f32x4 __attribute__((ext_vector_type(4)));
typedef float f32x16 __attribute__((ext_vector_type(16)));
typedef unsigned short us8 __attribute__((ext_vector_type(8)));
typedef unsigned u32x2 __attribute__((ext_vector_type(2)));

static __device__ __forceinline__ unsigned short f2h(float f) {
  return __builtin_bit_cast(unsigned short, (_Float16)f);   // HW RNE cvt
}
static __device__ __forceinline__ float h2f(unsigned short h) {
  return (float)__builtin_bit_cast(_Float16, h);
}
static __device__ __forceinline__ f32x4 mfma16(us8 a, us8 b, f32x4 c) {
  return __builtin_amdgcn_mfma_f32_16x16x32_f16(
      __builtin_bit_cast(h8, a), __builtin_bit_cast(h8, b), c, 0, 0, 0);
}
static __device__ __forceinline__ f32x16 mfma32(us8 a, us8 b, f32x16 c) {
  return __builtin_amdgcn_mfma_f32_32x32x16_f16(
      __builtin_bit_cast(h8, a), __builtin_bit_cast(h8, b), c, 0, 0, 0);
}
static __device__ __forceinline__ void gload16(const void* g, void* l) {
  __builtin_amdgcn_global_load_lds(
      (const __attribute__((address_space(1))) unsigned int*)g,
      (__attribute__((address_space(3))) unsigned int*)l, 16, 0, 0);
}
static __device__ __forceinline__ float exp2fast(float x) {
  float r; asm("v_exp_f32 %0, %1" : "=v"(r) : "v"(x)); return r;
}
static __device__ __forceinline__ unsigned cvtpkh(float lo, float hi) {
  unsigned r;
  asm("v_cvt_pkrtz_f16_f32 %0, %1, %2" : "=v"(r) : "v"(lo), "v"(hi));
  return r;
}
// permlane32_swap: ret[0]={a.lo,b.lo}, ret[1]={a.hi,b.hi} (lane halves)
static __device__ __forceinline__ void pl32swap(unsigned& a, unsigned& b) {
  u32x2 r = __builtin_amdgcn_permlane32_swap(a, b, false, false);
  a = r[0]; b = r[1];
}
// packed fragment offset within a 128x32 tile (elems), XOR-swizzled so that
// GEMM ds_read_b128 across lg-groups is bank-conflict-free.
static __device__ __forceinline__ int fragoff(int lg, int r) {
  return (((lg << 10) + (r << 3)) ^ (lg << 3));
}
// paired-row K/V LDS fragment byte offset for key/d index k at ks=0, hi half.
// Full offset for k-slice ks is off0 ^ (ks<<5): ks bits (5-6) are disjoint
// from the OR terms, so OR == XOR and the swizzle XOR commutes.
static __device__ __forceinline__ int fragoff0(int k, int hi) {
  return ((k >> 1) << 8) +
         (((((k & 1) << 7) | (hi << 4))) ^ (((k >> 1) & 7) << 4));
}

// ---------------------------------------------------------------------------
// Pack pass: f32 [M][1024] -> f16 in per-tile fragment order; block 2048
// additionally pre-scales the attention mask by LOG2E.
// ---------------------------------------------------------------------------
__global__ __launch_bounds__(256)
void pack_kernel(const float* __restrict__ X, const float* __restrict__ Wq,
                 const float* __restrict__ Wk, const float* __restrict__ Wv,
                 const float* __restrict__ Wo, const float* __restrict__ mask,
                 unsigned short* __restrict__ Xh,
                 unsigned short* __restrict__ Bh,
                 unsigned short* __restrict__ Oh,
                 float* __restrict__ maskl) {
  const int t = blockIdx.x;
  if (t == 2048) {   // mask prescale: B*S = 4096 floats
    const int i0 = threadIdx.x * 16;
#pragma unroll
    for (int j = 0; j < 4; ++j) {
      float4 v = *(const float4*)&mask[i0 + j * 4];
      v.x *= LOG2E; v.y *= LOG2E; v.z *= LOG2E; v.w *= LOG2E;
      *(float4*)&maskl[i0 + j * 4] = v;
    }
    return;
  }
  const float* src; unsigned short* dst;
  int smt, dmt, kt;
  if (t < 1024) { src = X; dst = Xh; smt = t >> 5; dmt = smt; kt = t & 31; }
  else {
    const int u = t - 1024, which = u >> 8, v = u & 255;
    smt = v >> 5; kt = v & 31;
    if (which == 0)      { src = Wq; dst = Bh; dmt = smt; }
    else if (which == 1) { src = Wk; dst = Bh; dmt = smt + 8; }
    else if (which == 2) { src = Wv; dst = Bh; dmt = smt + 16; }
    else                 { src = Wo; dst = Oh; dmt = smt; }
  }
  const size_t tb = ((size_t)(dmt * 32 + kt)) << 12;
#pragma unroll
  for (int it = 0; it < 2; ++it) {
    const int item = it * 256 + threadIdx.x;   // 0..511
    const int r = item >> 2, lg = item & 3;
    const float* sp = &src[(size_t)(smt * 128 + r) * HH + kt * 32 + lg * 8];
    const float4 a = *(const float4*)sp;
    const float4 b = *(const float4*)(sp + 4);
    const float vals[8] = {a.x, a.y, a.z, a.w, b.x, b.y, b.z, b.w};
    us8 h;
#pragma unroll
    for (int e = 0; e < 8; ++e) h[e] = f2h(vals[e]);
    *(us8*)&dst[tb + fragoff(lg, r)] = h;
  }
}

// ---------------------------------------------------------------------------
// Kernel 1: fused QKV projection, f16, 128x128 BK=32, DOUBLE-BUFFERED
// prefetch (stage k+1 while computing k; one barrier per K-step).
// ---------------------------------------------------------------------------
__global__ __launch_bounds__(256, 3)
void qkv_gemm_kernel(const unsigned short* __restrict__ Ah_,
                     const unsigned short* __restrict__ Bh_,
                     const float* __restrict__ bq, const float* __restrict__ bk,
                     const float* __restrict__ bv,
                     unsigned short* __restrict__ qb,
                     unsigned short* __restrict__ kb,
                     unsigned short* __restrict__ vt) {
  __shared__ __align__(16) unsigned short tiles[2][2][4096];
  const int tid = threadIdx.x, lane = tid & 63, wid = tid >> 6;
  const int l16 = lane & 15, lg = lane >> 4;
  const int wr = wid >> 1, wc = wid & 1;
  const int mt0 = blockIdx.y, nt0 = blockIdx.x;

  const unsigned short* gA = Ah_ + (((size_t)mt0 * 32) << 12);
  const unsigned short* gB = Bh_ + (((size_t)nt0 * 32) << 12);

#define GSTAGE(buf, kt_)                                                       \
  {                                                                            \
    const size_t ko_ = ((size_t)(kt_)) << 12;                                  \
    _Pragma("unroll")                                                          \
    for (int it_ = 0; it_ < 2; ++it_) {                                        \
      const int c_ = it_ * 256 + tid;                                          \
      gload16(gA + ko_ + c_ * 8, (char*)&tiles[buf][0][0] + c_ * 16);          \
      gload16(gB + ko_ + c_ * 8, (char*)&tiles[buf][1][0] + c_ * 16);          \
    }                                                                          \
  }

  f32x4 acc[4][4] = {};
  GSTAGE(0, 0)
  __syncthreads();
  for (int kt = 0; kt < 32; ++kt) {
    const int buf = kt & 1;
    if (kt + 1 < 32) GSTAGE(buf ^ 1, kt + 1)

    us8 a[4], b[4];
#pragma unroll
    for (int t = 0; t < 4; ++t) {
      a[t] = *(const us8*)&tiles[buf][0][fragoff(lg, wr * 64 + t * 16 + l16)];
      b[t] = *(const us8*)&tiles[buf][1][fragoff(lg, wc * 64 + t * 16 + l16)];
    }
#pragma unroll
    for (int mt = 0; mt < 4; ++mt)
#pragma unroll
      for (int nt = 0; nt < 4; ++nt)
        acc[mt][nt] = mfma16(a[mt], b[nt], acc[mt][nt]);
    __syncthreads();   // drains this iter's prefetch + all LDS reads
  }
#undef GSTAGE

  const int m0 = mt0 * 128, n0 = nt0 * 128;
#pragma unroll
  for (int nt = 0; nt < 4; ++nt) {
    const int col = n0 + wc * 64 + nt * 16 + l16;   // 0..3071
    const int which = col >> 10, nn = col & 1023;
    const float bias = (which == 0) ? bq[nn] : ((which == 1) ? bk[nn] : bv[nn]);
    const int h = nn >> 6, d = nn & 63;
#pragma unroll
    for (int mt = 0; mt < 4; ++mt) {
      const int row0 = m0 + wr * 64 + mt * 16 + lg * 4;   // si0 multiple of 4
      const int bi = row0 >> 11, si0 = row0 & 2047;
      const size_t head = (size_t)(bi * NHH + h);
      if (which == 2) {
        ushort4 vv;
#pragma unroll
        for (int reg = 0; reg < 4; ++reg)
          ((unsigned short*)&vv)[reg] = f2h(acc[mt][nt][reg] + bias);
        *(ushort4*)&vt[(head * HDD + d) * SS + si0] = vv;
      } else {
#pragma unroll
        for (int reg = 0; reg < 4; ++reg) {
          const unsigned short v16 = f2h(acc[mt][nt][reg] + bias);
          if (which == 0) qb[(head * SS + si0 + reg) * HDD + d] = v16;
          else            kb[(head * SS + si0 + reg) * HDD + d] = v16;
        }
      }
    }
  }
}

// ---------------------------------------------------------------------------
// Kernel 2: flash attention, split-K(4). Block = 8 waves x 32 q-rows, keys
// [quarter*512, quarter*512+512). Fixed-max softmax P = 2^(s+mask).
// Paired-row K/V LDS (2-way = free). Unnormalized O (f16) + l per quarter.
// ---------------------------------------------------------------------------
__global__ __launch_bounds__(512, 8)
void attn_kernel(const unsigned short* __restrict__ qb,
                 const unsigned short* __restrict__ kbuf,
                 const unsigned short* __restrict__ vt,
                 const float* __restrict__ maskl,
                 unsigned short* __restrict__ Op0,
                 unsigned short* __restrict__ Op1,
                 unsigned short* __restrict__ Op2,
                 unsigned short* __restrict__ Op3,
                 float* __restrict__ Ls) {          // [4][32][S]
  __shared__ __align__(16) unsigned short Klds[2][4096];
  __shared__ __align__(16) unsigned short Vlds[2][4096];
  __shared__ __align__(16) float Msk[512];

  const int tid = threadIdx.x, lane = tid & 63, w = tid >> 6;
  const int q = lane & 31, hi = lane >> 5;
  const int bh = blockIdx.x;          // 0..31 ; XCD = bh%8 for all its blocks
  const int bi = bh >> 4, h = bh & 15;
  const int quarter = blockIdx.y >> 3;
  const int q0 = (blockIdx.y & 7) * 256 + w * 32;
  const int kbase = quarter * 512;
  const size_t bhS = (size_t)bh * SS;
  const int qrow = q0 + q;            // this lane's q-row (s index)

  us8 qf[4];
#pragma unroll
  for (int ks = 0; ks < 4; ++ks)
    qf[ks] = *(const us8*)&qb[(bhS + qrow) * HDD + ks * 16 + hi * 8];

  // precomputed paired-row fragment offsets (ks term applied by XOR)
  const int koff0 = fragoff0(q, hi);
  const int koff1 = fragoff0(32 + q, hi);

  f32x16 o0 = {}, o1 = {};
  float lrun = 0.0f;

#define STAGE(buf, kt_)                                                        \
  {                                                                            \
    const int key0_ = kbase + (kt_) * 64;                                      \
    const int row_ = tid >> 4;          /* paired LDS row 0..31 */             \
    const int ss_ = (tid & 15) ^ (row_ & 7);                                   \
    const int kd_ = 2 * row_ + (ss_ >> 3);                                     \
    const int el_ = (ss_ & 7) * 8;                                             \
    gload16(&kbuf[(bhS + key0_ + kd_) * HDD + el_],                            \
            (char*)&Klds[buf][0] + tid * 16);                                  \
    gload16(&vt[((size_t)bh * HDD + kd_) * SS + key0_ + el_],                  \
            (char*)&Vlds[buf][0] + tid * 16);                                  \
  }

  // stage this quarter's mask slice (512 f32 = 2KB) once
  if (w < 2)
    gload16(&maskl[bi * SS + kbase + tid * 4], (char*)&Msk[0] + tid * 16);
  STAGE(0, 0)
  __syncthreads();

  for (int kt = 0; kt < 8; ++kt) {
    const int buf = kt & 1;
    if (kt + 1 < 8) STAGE(buf ^ 1, kt + 1)
    const char* kb0 = (const char*)&Klds[0][0] + buf * 8192;
    const char* vb0 = (const char*)&Vlds[0][0] + buf * 8192;

    // ---- S^T = K . Q^T : rows = 64 keys (2 blocks), cols = 32 q ----
    f32x16 s0 = {}, s1 = {};
    __builtin_amdgcn_s_setprio(1);
#pragma unroll
    for (int ks = 0; ks < 4; ++ks) {
      const us8 kf0 = *(const us8*)(kb0 + (koff0 ^ (ks << 5)));
      const us8 kf1 = *(const us8*)(kb0 + (koff1 ^ (ks << 5)));
      s0 = mfma32(kf0, qf[ks], s0);
      s1 = mfma32(kf1, qf[ks], s1);
    }
    __builtin_amdgcn_s_setprio(0);

    // ---- P = 2^(s*C1 + mask) directly: no max tracking (s bounded) ----
#pragma unroll
    for (int g = 0; g < 4; ++g) {
      const float4 m0v = *(const float4*)&Msk[kt * 64 + g * 8 + hi * 4];
      const float4 m1v = *(const float4*)&Msk[kt * 64 + 32 + g * 8 + hi * 4];
      const float mm0[4] = {m0v.x, m0v.y, m0v.z, m0v.w};
      const float mm1[4] = {m1v.x, m1v.y, m1v.z, m1v.w};
#pragma unroll
      for (int j = 0; j < 4; ++j) {
        const int reg = g * 4 + j;
        s0[reg] = exp2fast(s0[reg] * C1 + mm0[j]);
        s1[reg] = exp2fast(s1[reg] * C1 + mm1[j]);
      }
    }
    // row-sum: 4 parallel accumulator chains
    float pa = 0.0f, pb_ = 0.0f, pc = 0.0f, pd = 0.0f;
#pragma unroll
    for (int g = 0; g < 4; ++g) {
      pa += s0[g * 4];     pb_ += s0[g * 4 + 1];
      pc += s0[g * 4 + 2]; pd += s0[g * 4 + 3];
      pa += s1[g * 4];     pb_ += s1[g * 4 + 1];
      pc += s1[g * 4 + 2]; pd += s1[g * 4 + 3];
    }
    float ps = (pa + pb_) + (pc + pd);
    ps += __shfl_xor(ps, 32);
    lrun += ps;

    // ---- P -> B-frags: cvt_pkrtz pairs + permlane32_swap ----
    us8 pb[4];
    {
      unsigned C[8];
#pragma unroll
      for (int j = 0; j < 8; ++j) C[j] = cvtpkh(s0[2 * j], s0[2 * j + 1]);
      pl32swap(C[0], C[2]); pl32swap(C[1], C[3]);
      pl32swap(C[4], C[6]); pl32swap(C[5], C[7]);
      union { unsigned wd[4]; us8 v; } u0, u1;
      u0.wd[0] = C[0]; u0.wd[1] = C[1]; u0.wd[2] = C[2]; u0.wd[3] = C[3];
      u1.wd[0] = C[4]; u1.wd[1] = C[5]; u1.wd[2] = C[6]; u1.wd[3] = C[7];
      pb[0] = u0.v; pb[1] = u1.v;
#pragma unroll
      for (int j = 0; j < 8; ++j) C[j] = cvtpkh(s1[2 * j], s1[2 * j + 1]);
      pl32swap(C[0], C[2]); pl32swap(C[1], C[3]);
      pl32swap(C[4], C[6]); pl32swap(C[5], C[7]);
      u0.wd[0] = C[0]; u0.wd[1] = C[1]; u0.wd[2] = C[2]; u0.wd[3] = C[3];
      u1.wd[0] = C[4]; u1.wd[1] = C[5]; u1.wd[2] = C[6]; u1.wd[3] = C[7];
      pb[2] = u0.v; pb[3] = u1.v;
    }

    // ---- O^T += V^T . P^T ----
    __builtin_amdgcn_s_setprio(1);
#pragma unroll
    for (int ks = 0; ks < 4; ++ks) {
      const us8 vf0 = *(const us8*)(vb0 + (koff0 ^ (ks << 5)));
      const us8 vf1 = *(const us8*)(vb0 + (koff1 ^ (ks << 5)));
      o0 = mfma32(vf0, pb[ks], o0);
      o1 = mfma32(vf1, pb[ks], o1);
    }
    __builtin_amdgcn_s_setprio(0);

    __syncthreads();   // next-tile staging drained; all done reading cur
  }

  // ---- epilogue: unnormalized O (f16) + l ----
  unsigned short* opq = (quarter == 0) ? Op0 : (quarter == 1) ? Op1
                       : (quarter == 2) ? Op2 : Op3;
  unsigned short* op = opq + (bhS + qrow) * HDD;
#pragma unroll
  for (int g = 0; g < 4; ++g) {
    ushort4 v0, v1;
#pragma unroll
    for (int j = 0; j < 4; ++j) {
      ((unsigned short*)&v0)[j] = f2h(o0[g * 4 + j]);
      ((unsigned short*)&v1)[j] = f2h(o1[g * 4 + j]);
    }
    *(ushort4*)&op[g * 8 + hi * 4]      = v0;
    *(ushort4*)&op[32 + g * 8 + hi * 4] = v1;
  }
  if (hi == 0)
    Ls[((size_t)quarter * 32 + bh) * SS + qrow] = lrun;
#undef STAGE
}

// ---------------------------------------------------------------------------
// Kernel 2b: combine 4 split-K parts -> packed f16 ctx (out_gemm A order).
// Same implicit max in all parts: out = (O0+O1+O2+O3)/(l0+l1+l2+l3).
// ---------------------------------------------------------------------------
__global__ __launch_bounds__(256)
void combine_kernel(const unsigned short* __restrict__ Op0,
                    const unsigned short* __restrict__ Op1,
                    const unsigned short* __restrict__ Op2,
                    const unsigned short* __restrict__ Op3,
                    const float* __restrict__ Ls,
                    unsigned short* __restrict__ Ch) {
  const int gid = blockIdx.x * 256 + threadIdx.x;
  const int row = gid >> 2, qtr = gid & 3;     // row 0..65535, 16 cols each
  const int bh = row >> 11, s = row & 2047;
  const int bi = bh >> 4, h = bh & 15;

  const float tot = (Ls[row] + Ls[65536 + row]) +
                    (Ls[131072 + row] + Ls[196608 + row]);
  const float rinv = 1.0f / tot;

  const int d0 = qtr * 16;
  const us8* p0 = (const us8*)&Op0[(size_t)row * HDD + d0];
  const us8* p1 = (const us8*)&Op1[(size_t)row * HDD + d0];
  const us8* p2 = (const us8*)&Op2[(size_t)row * HDD + d0];
  const us8* p3 = (const us8*)&Op3[(size_t)row * HDD + d0];
  const us8 a0 = p0[0], a1 = p0[1];
  const us8 b0 = p1[0], b1 = p1[1];
  const us8 c0 = p2[0], c1 = p2[1];
  const us8 d0v = p3[0], d1 = p3[1];

  const int mrow = bi * SS + s;
  const int mt = mrow >> 7, r = mrow & 127;
#pragma unroll
  for (int j4 = 0; j4 < 4; ++j4) {
    const int col = h * 64 + d0 + j4 * 4;
    const int kt2 = col >> 5, lg2 = (col >> 3) & 3, e0 = col & 7;
    const size_t off = (((size_t)(mt * 32 + kt2)) << 12) + fragoff(lg2, r) + e0;
    ushort4 hv;
#pragma unroll
    for (int j = 0; j < 4; ++j) {
      const int k = j4 * 4 + j;
      const float va = h2f(k < 8 ? a0[k] : a1[k - 8]);
      const float vb = h2f(k < 8 ? b0[k] : b1[k - 8]);
      const float vc = h2f(k < 8 ? c0[k] : c1[k - 8]);
      const float vd = h2f(k < 8 ? d0v[k] : d1[k - 8]);
      ((unsigned short*)&hv)[j] = f2h(((va + vb) + (vc + vd)) * rinv);
    }
    *(ushort4*)&Ch[off] = hv;
  }
}

// ---------------------------------------------------------------------------
// Kernel 3: output projection, double-buffered prefetch, fp32 out + bias.
// ---------------------------------------------------------------------------
__global__ __launch_bounds__(256, 3)
void out_gemm_kernel(const unsigned short* __restrict__ Ah_,
                     const unsigned short* __restrict__ Bh_,
                     const float* __restrict__ bo, float* __restrict__ out) {
  __shared__ __align__(16) unsigned short tiles[2][2][4096];
  const int tid = threadIdx.x, lane = tid & 63, wid = tid >> 6;
  const int l16 = lane & 15, lg = lane >> 4;
  const int wr = wid >> 1, wc = wid & 1;
  const int mt0 = blockIdx.y, nt0 = blockIdx.x;

  const unsigned short* gA = Ah_ + (((size_t)mt0 * 32) << 12);
  const unsigned short* gB = Bh_ + (((size_t)nt0 * 32) << 12);

#define GSTAGE(buf, kt_)                                                       \
  {                                                                            \
    const size_t ko_ = ((size_t)(kt_)) << 12;                                  \
    _Pragma("unroll")                                                          \
    for (int it_ = 0; it_ < 2; ++it_) {                                        \
      const int c_ = it_ * 256 + tid;                                          \
      gload16(gA + ko_ + c_ * 8, (char*)&tiles[buf][0][0] + c_ * 16);          \
      gload16(gB + ko_ + c_ * 8, (char*)&tiles[buf][1][0] + c_ * 16);          \
    }                                                                          \
  }

  f32x4 acc[4][4] = {};
  GSTAGE(0, 0)
  __syncthreads();
  for (int kt = 0; kt < 32; ++kt) {
    const int buf = kt & 1;
    if (kt + 1 < 32) GSTAGE(buf ^ 1, kt + 1)

    us8 a[4], b[4];
#pragma unroll
    for (int t = 0; t < 4; ++t) {
      a[t] = *(const us8*)&tiles[buf][0][fragoff(lg, wr * 64 + t * 16 + l16)];
      b[t] = *(const us8*)&tiles[buf][1][fragoff(lg, wc * 64 + t * 16 + l16)];
    }
#pragma unroll
    for (int mt = 0; mt < 4; ++mt)
#pragma unroll
      for (int nt = 0; nt < 4; ++nt)
        acc[mt][nt] = mfma16(a[mt], b[nt], acc[mt][nt]);
    __syncthreads();
  }
#undef GSTAGE

  const int m0 = mt0 * 128, n0 = nt0 * 128;
#pragma unroll
  for (int nt = 0; nt < 4; ++nt) {
    const int col = n0 + wc * 64 + nt * 16 + l16;
    const float bias = bo[col];
#pragma unroll
    for (int mt = 0; mt < 4; ++mt)
#pragma unroll
      for (int reg = 0; reg < 4; ++reg) {
        const int row = m0 + wr * 64 + mt * 16 + lg * 4 + reg;
        out[(size_t)row * HH + col] = acc[mt][nt][reg] + bias;
      }
  }
}

// ---------------------------------------------------------------------------
extern "C" void kernel_launch(void* const* d_in, const int* in_sizes, int n_in,
                              void* d_out, int out_size, void* d_ws, size_t ws_size,
                              hipStream_t stream) {
  const float* X    = (const float*)d_in[0];
  const float* mask = (const float*)d_in[1];
  const float* Wq   = (const float*)d_in[2];
  const float* bq   = (const float*)d_in[3];
  const float* Wk   = (const float*)d_in[4];
  const float* bk   = (const float*)d_in[5];
  const float* Wv   = (const float*)d_in[6];
  const float* bv   = (const float*)d_in[7];
  const float* Wo   = (const float*)d_in[8];
  const float* bo   = (const float*)d_in[9];
  float* out = (float*)d_out;

  unsigned char* w = (unsigned char*)d_ws;
  const size_t MB = 1024 * 1024;
  // layout (time-multiplexed aliases):
  //  0- 8: Xh (qkv A)        -> Op2 (attn quarter 2)
  //  8-16: Bh (qkv B, 6MB)   -> Op3 (attn quarter 3)
  // 16-24: qb
  // 24-32: kb                -> Ch (combine output)
  // 32-40: vt
  // 40-48: Op0   48-56: Op1
  // 56-58: Oh (Wo packed)    58-59: Ls    59+: maskl
  unsigned short* Xh  = (unsigned short*)(w);
  unsigned short* Bh  = (unsigned short*)(w + 8 * MB);
  unsigned short* qb  = (unsigned short*)(w + 16 * MB);
  unsigned short* kb  = (unsigned short*)(w + 24 * MB);
  unsigned short* vt  = (unsigned short*)(w + 32 * MB);
  unsigned short* Op0 = (unsigned short*)(w + 40 * MB);
  unsigned short* Op1 = (unsigned short*)(w + 48 * MB);
  unsigned short* Op2 = Xh;
  unsigned short* Op3 = Bh;
  unsigned short* Oh  = (unsigned short*)(w + 56 * MB);
  float*          Ls  = (float*)(w + 58 * MB);
  float*       maskl  = (float*)(w + 59 * MB);
  unsigned short* Ch  = kb;   // combine output over dead K buffer

  pack_kernel<<<2049, 256, 0, stream>>>(X, Wq, Wk, Wv, Wo, mask,
                                        Xh, Bh, Oh, maskl);
  qkv_gemm_kernel<<<dim3(24, 32), 256, 0, stream>>>(Xh, Bh, bq, bk, bv,
                                                    qb, kb, vt);
  attn_kernel<<<dim3(32, 32), 512, 0, stream>>>(qb, kb, vt, maskl,
                                                Op0, Op1, Op2, Op3, Ls);
  combine_kernel<<<1024, 256, 0, stream>>>(Op0, Op1, Op2, Op3, Ls, Ch);
  out_gemm_kernel<<<dim3(8, 32), 256, 0, stream>>>(Ch, Oh, bo, out);
}

// Round 8
// 200.228 us; speedup vs baseline: 2.1828x; 2.1828x over previous
//
#include <hip/hip_runtime.h>

// MHA forward, MI355X gfx950. B=2 S=2048 H=1024 NH=16 HD=64, fp32 I/O.
// R8: R7 with the launch-bounds spill fixed (no min-waves clamp: R7's
//     __launch_bounds__(512,8) capped VGPR at 64 -> accumulators spilled,
//     1.3GB scratch traffic). Split-K(4) attn, XOR-algebra fragment offsets,
//     double-buffered prefetch GEMMs.

#define BB   2
#define SS   2048
#define HH   1024
#define NHH  16
#define HDD  64

#define LOG2E 1.4426950408889634f
#define C1    (0.125f * LOG2E)   // qk scale folded into log2 domain

typedef _Float16 h8 __attribute__((ext_vector_type(8)));
typedef float f32x4 __attribute__((ext_vector_type(4)));
typedef float f32x16 __attribute__((ext_vector_type(16)));
typedef unsigned short us8 __attribute__((ext_vector_type(8)));
typedef unsigned u32x2 __attribute__((ext_vector_type(2)));

static __device__ __forceinline__ unsigned short f2h(float f) {
  return __builtin_bit_cast(unsigned short, (_Float16)f);   // HW RNE cvt
}
static __device__ __forceinline__ float h2f(unsigned short h) {
  return (float)__builtin_bit_cast(_Float16, h);
}
static __device__ __forceinline__ f32x4 mfma16(us8 a, us8 b, f32x4 c) {
  return __builtin_amdgcn_mfma_f32_16x16x32_f16(
      __builtin_bit_cast(h8, a), __builtin_bit_cast(h8, b), c, 0, 0, 0);
}
static __device__ __forceinline__ f32x16 mfma32(us8 a, us8 b, f32x16 c) {
  return __builtin_amdgcn_mfma_f32_32x32x16_f16(
      __builtin_bit_cast(h8, a), __builtin_bit_cast(h8, b), c, 0, 0, 0);
}
static __device__ __forceinline__ void gload16(const void* g, void* l) {
  __builtin_amdgcn_global_load_lds(
      (const __attribute__((address_space(1))) unsigned int*)g,
      (__attribute__((address_space(3))) unsigned int*)l, 16, 0, 0);
}
static __device__ __forceinline__ float exp2fast(float x) {
  float r; asm("v_exp_f32 %0, %1" : "=v"(r) : "v"(x)); return r;
}
static __device__ __forceinline__ unsigned cvtpkh(float lo, float hi) {
  unsigned r;
  asm("v_cvt_pkrtz_f16_f32 %0, %1, %2" : "=v"(r) : "v"(lo), "v"(hi));
  return r;
}
// permlane32_swap: ret[0]={a.lo,b.lo}, ret[1]={a.hi,b.hi} (lane halves)
static __device__ __forceinline__ void pl32swap(unsigned& a, unsigned& b) {
  u32x2 r = __builtin_amdgcn_permlane32_swap(a, b, false, false);
  a = r[0]; b = r[1];
}
// packed fragment offset within a 128x32 tile (elems), XOR-swizzled so that
// GEMM ds_read_b128 across lg-groups is bank-conflict-free.
static __device__ __forceinline__ int fragoff(int lg, int r) {
  return (((lg << 10) + (r << 3)) ^ (lg << 3));
}
// paired-row K/V LDS fragment byte offset for key/d index k at ks=0, hi half.
// Full offset for k-slice ks is off0 ^ (ks<<5): ks bits (5-6) are disjoint
// from the OR terms, so OR == XOR and the swizzle XOR commutes.
static __device__ __forceinline__ int fragoff0(int k, int hi) {
  return ((k >> 1) << 8) +
         (((((k & 1) << 7) | (hi << 4))) ^ (((k >> 1) & 7) << 4));
}

// ---------------------------------------------------------------------------
// Pack pass: f32 [M][1024] -> f16 in per-tile fragment order; block 2048
// additionally pre-scales the attention mask by LOG2E.
// ---------------------------------------------------------------------------
__global__ __launch_bounds__(256)
void pack_kernel(const float* __restrict__ X, const float* __restrict__ Wq,
                 const float* __restrict__ Wk, const float* __restrict__ Wv,
                 const float* __restrict__ Wo, const float* __restrict__ mask,
                 unsigned short* __restrict__ Xh,
                 unsigned short* __restrict__ Bh,
                 unsigned short* __restrict__ Oh,
                 float* __restrict__ maskl) {
  const int t = blockIdx.x;
  if (t == 2048) {   // mask prescale: B*S = 4096 floats
    const int i0 = threadIdx.x * 16;
#pragma unroll
    for (int j = 0; j < 4; ++j) {
      float4 v = *(const float4*)&mask[i0 + j * 4];
      v.x *= LOG2E; v.y *= LOG2E; v.z *= LOG2E; v.w *= LOG2E;
      *(float4*)&maskl[i0 + j * 4] = v;
    }
    return;
  }
  const float* src; unsigned short* dst;
  int smt, dmt, kt;
  if (t < 1024) { src = X; dst = Xh; smt = t >> 5; dmt = smt; kt = t & 31; }
  else {
    const int u = t - 1024, which = u >> 8, v = u & 255;
    smt = v >> 5; kt = v & 31;
    if (which == 0)      { src = Wq; dst = Bh; dmt = smt; }
    else if (which == 1) { src = Wk; dst = Bh; dmt = smt + 8; }
    else if (which == 2) { src = Wv; dst = Bh; dmt = smt + 16; }
    else                 { src = Wo; dst = Oh; dmt = smt; }
  }
  const size_t tb = ((size_t)(dmt * 32 + kt)) << 12;
#pragma unroll
  for (int it = 0; it < 2; ++it) {
    const int item = it * 256 + threadIdx.x;   // 0..511
    const int r = item >> 2, lg = item & 3;
    const float* sp = &src[(size_t)(smt * 128 + r) * HH + kt * 32 + lg * 8];
    const float4 a = *(const float4*)sp;
    const float4 b = *(const float4*)(sp + 4);
    const float vals[8] = {a.x, a.y, a.z, a.w, b.x, b.y, b.z, b.w};
    us8 h;
#pragma unroll
    for (int e = 0; e < 8; ++e) h[e] = f2h(vals[e]);
    *(us8*)&dst[tb + fragoff(lg, r)] = h;
  }
}

// ---------------------------------------------------------------------------
// Kernel 1: fused QKV projection, f16, 128x128 BK=32, DOUBLE-BUFFERED
// prefetch (stage k+1 while computing k; one barrier per K-step).
// ---------------------------------------------------------------------------
__global__ __launch_bounds__(256, 3)
void qkv_gemm_kernel(const unsigned short* __restrict__ Ah_,
                     const unsigned short* __restrict__ Bh_,
                     const float* __restrict__ bq, const float* __restrict__ bk,
                     const float* __restrict__ bv,
                     unsigned short* __restrict__ qb,
                     unsigned short* __restrict__ kb,
                     unsigned short* __restrict__ vt) {
  __shared__ __align__(16) unsigned short tiles[2][2][4096];
  const int tid = threadIdx.x, lane = tid & 63, wid = tid >> 6;
  const int l16 = lane & 15, lg = lane >> 4;
  const int wr = wid >> 1, wc = wid & 1;
  const int mt0 = blockIdx.y, nt0 = blockIdx.x;

  const unsigned short* gA = Ah_ + (((size_t)mt0 * 32) << 12);
  const unsigned short* gB = Bh_ + (((size_t)nt0 * 32) << 12);

#define GSTAGE(buf, kt_)                                                       \
  {                                                                            \
    const size_t ko_ = ((size_t)(kt_)) << 12;                                  \
    _Pragma("unroll")                                                          \
    for (int it_ = 0; it_ < 2; ++it_) {                                        \
      const int c_ = it_ * 256 + tid;                                          \
      gload16(gA + ko_ + c_ * 8, (char*)&tiles[buf][0][0] + c_ * 16);          \
      gload16(gB + ko_ + c_ * 8, (char*)&tiles[buf][1][0] + c_ * 16);          \
    }                                                                          \
  }

  f32x4 acc[4][4] = {};
  GSTAGE(0, 0)
  __syncthreads();
  for (int kt = 0; kt < 32; ++kt) {
    const int buf = kt & 1;
    if (kt + 1 < 32) GSTAGE(buf ^ 1, kt + 1)

    us8 a[4], b[4];
#pragma unroll
    for (int t = 0; t < 4; ++t) {
      a[t] = *(const us8*)&tiles[buf][0][fragoff(lg, wr * 64 + t * 16 + l16)];
      b[t] = *(const us8*)&tiles[buf][1][fragoff(lg, wc * 64 + t * 16 + l16)];
    }
#pragma unroll
    for (int mt = 0; mt < 4; ++mt)
#pragma unroll
      for (int nt = 0; nt < 4; ++nt)
        acc[mt][nt] = mfma16(a[mt], b[nt], acc[mt][nt]);
    __syncthreads();   // drains this iter's prefetch + all LDS reads
  }
#undef GSTAGE

  const int m0 = mt0 * 128, n0 = nt0 * 128;
#pragma unroll
  for (int nt = 0; nt < 4; ++nt) {
    const int col = n0 + wc * 64 + nt * 16 + l16;   // 0..3071
    const int which = col >> 10, nn = col & 1023;
    const float bias = (which == 0) ? bq[nn] : ((which == 1) ? bk[nn] : bv[nn]);
    const int h = nn >> 6, d = nn & 63;
#pragma unroll
    for (int mt = 0; mt < 4; ++mt) {
      const int row0 = m0 + wr * 64 + mt * 16 + lg * 4;   // si0 multiple of 4
      const int bi = row0 >> 11, si0 = row0 & 2047;
      const size_t head = (size_t)(bi * NHH + h);
      if (which == 2) {
        ushort4 vv;
#pragma unroll
        for (int reg = 0; reg < 4; ++reg)
          ((unsigned short*)&vv)[reg] = f2h(acc[mt][nt][reg] + bias);
        *(ushort4*)&vt[(head * HDD + d) * SS + si0] = vv;
      } else {
#pragma unroll
        for (int reg = 0; reg < 4; ++reg) {
          const unsigned short v16 = f2h(acc[mt][nt][reg] + bias);
          if (which == 0) qb[(head * SS + si0 + reg) * HDD + d] = v16;
          else            kb[(head * SS + si0 + reg) * HDD + d] = v16;
        }
      }
    }
  }
}

// ---------------------------------------------------------------------------
// Kernel 2: flash attention, split-K(4). Block = 8 waves x 32 q-rows, keys
// [quarter*512, quarter*512+512). Fixed-max softmax P = 2^(s+mask).
// Paired-row K/V LDS (2-way = free). Unnormalized O (f16) + l per quarter.
// NOTE: no min-waves in launch_bounds — R7's ",8" forced a 64-VGPR cap and
// spilled the f32x16 accumulators to scratch (1.3GB traffic, 5.6x slower).
// ---------------------------------------------------------------------------
__global__ __launch_bounds__(512)
void attn_kernel(const unsigned short* __restrict__ qb,
                 const unsigned short* __restrict__ kbuf,
                 const unsigned short* __restrict__ vt,
                 const float* __restrict__ maskl,
                 unsigned short* __restrict__ Op0,
                 unsigned short* __restrict__ Op1,
                 unsigned short* __restrict__ Op2,
                 unsigned short* __restrict__ Op3,
                 float* __restrict__ Ls) {          // [4][32][S]
  __shared__ __align__(16) unsigned short Klds[2][4096];
  __shared__ __align__(16) unsigned short Vlds[2][4096];
  __shared__ __align__(16) float Msk[512];

  const int tid = threadIdx.x, lane = tid & 63, w = tid >> 6;
  const int q = lane & 31, hi = lane >> 5;
  const int bh = blockIdx.x;          // 0..31 ; XCD = bh%8 for all its blocks
  const int bi = bh >> 4, h = bh & 15;
  const int quarter = blockIdx.y >> 3;
  const int q0 = (blockIdx.y & 7) * 256 + w * 32;
  const int kbase = quarter * 512;
  const size_t bhS = (size_t)bh * SS;
  const int qrow = q0 + q;            // this lane's q-row (s index)

  us8 qf[4];
#pragma unroll
  for (int ks = 0; ks < 4; ++ks)
    qf[ks] = *(const us8*)&qb[(bhS + qrow) * HDD + ks * 16 + hi * 8];

  // precomputed paired-row fragment offsets (ks term applied by XOR)
  const int koff0 = fragoff0(q, hi);
  const int koff1 = fragoff0(32 + q, hi);

  f32x16 o0 = {}, o1 = {};
  float lrun = 0.0f;

#define STAGE(buf, kt_)                                                        \
  {                                                                            \
    const int key0_ = kbase + (kt_) * 64;                                      \
    const int row_ = tid >> 4;          /* paired LDS row 0..31 */             \
    const int ss_ = (tid & 15) ^ (row_ & 7);                                   \
    const int kd_ = 2 * row_ + (ss_ >> 3);                                     \
    const int el_ = (ss_ & 7) * 8;                                             \
    gload16(&kbuf[(bhS + key0_ + kd_) * HDD + el_],                            \
            (char*)&Klds[buf][0] + tid * 16);                                  \
    gload16(&vt[((size_t)bh * HDD + kd_) * SS + key0_ + el_],                  \
            (char*)&Vlds[buf][0] + tid * 16);                                  \
  }

  // stage this quarter's mask slice (512 f32 = 2KB) once
  if (w < 2)
    gload16(&maskl[bi * SS + kbase + tid * 4], (char*)&Msk[0] + tid * 16);
  STAGE(0, 0)
  __syncthreads();

  for (int kt = 0; kt < 8; ++kt) {
    const int buf = kt & 1;
    if (kt + 1 < 8) STAGE(buf ^ 1, kt + 1)
    const char* kb0 = (const char*)&Klds[0][0] + buf * 8192;
    const char* vb0 = (const char*)&Vlds[0][0] + buf * 8192;

    // ---- S^T = K . Q^T : rows = 64 keys (2 blocks), cols = 32 q ----
    f32x16 s0 = {}, s1 = {};
    __builtin_amdgcn_s_setprio(1);
#pragma unroll
    for (int ks = 0; ks < 4; ++ks) {
      const us8 kf0 = *(const us8*)(kb0 + (koff0 ^ (ks << 5)));
      const us8 kf1 = *(const us8*)(kb0 + (koff1 ^ (ks << 5)));
      s0 = mfma32(kf0, qf[ks], s0);
      s1 = mfma32(kf1, qf[ks], s1);
    }
    __builtin_amdgcn_s_setprio(0);

    // ---- P = 2^(s*C1 + mask) directly: no max tracking (s bounded) ----
#pragma unroll
    for (int g = 0; g < 4; ++g) {
      const float4 m0v = *(const float4*)&Msk[kt * 64 + g * 8 + hi * 4];
      const float4 m1v = *(const float4*)&Msk[kt * 64 + 32 + g * 8 + hi * 4];
      const float mm0[4] = {m0v.x, m0v.y, m0v.z, m0v.w};
      const float mm1[4] = {m1v.x, m1v.y, m1v.z, m1v.w};
#pragma unroll
      for (int j = 0; j < 4; ++j) {
        const int reg = g * 4 + j;
        s0[reg] = exp2fast(s0[reg] * C1 + mm0[j]);
        s1[reg] = exp2fast(s1[reg] * C1 + mm1[j]);
      }
    }
    // row-sum: 4 parallel accumulator chains
    float pa = 0.0f, pb_ = 0.0f, pc = 0.0f, pd = 0.0f;
#pragma unroll
    for (int g = 0; g < 4; ++g) {
      pa += s0[g * 4];     pb_ += s0[g * 4 + 1];
      pc += s0[g * 4 + 2]; pd += s0[g * 4 + 3];
      pa += s1[g * 4];     pb_ += s1[g * 4 + 1];
      pc += s1[g * 4 + 2]; pd += s1[g * 4 + 3];
    }
    float ps = (pa + pb_) + (pc + pd);
    ps += __shfl_xor(ps, 32);
    lrun += ps;

    // ---- P -> B-frags: cvt_pkrtz pairs + permlane32_swap ----
    us8 pb[4];
    {
      unsigned C[8];
#pragma unroll
      for (int j = 0; j < 8; ++j) C[j] = cvtpkh(s0[2 * j], s0[2 * j + 1]);
      pl32swap(C[0], C[2]); pl32swap(C[1], C[3]);
      pl32swap(C[4], C[6]); pl32swap(C[5], C[7]);
      union { unsigned wd[4]; us8 v; } u0, u1;
      u0.wd[0] = C[0]; u0.wd[1] = C[1]; u0.wd[2] = C[2]; u0.wd[3] = C[3];
      u1.wd[0] = C[4]; u1.wd[1] = C[5]; u1.wd[2] = C[6]; u1.wd[3] = C[7];
      pb[0] = u0.v; pb[1] = u1.v;
#pragma unroll
      for (int j = 0; j < 8; ++j) C[j] = cvtpkh(s1[2 * j], s1[2 * j + 1]);
      pl32swap(C[0], C[2]); pl32swap(C[1], C[3]);
      pl32swap(C[4], C[6]); pl32swap(C[5], C[7]);
      u0.wd[0] = C[0]; u0.wd[1] = C[1]; u0.wd[2] = C[2]; u0.wd[3] = C[3];
      u1.wd[0] = C[4]; u1.wd[1] = C[5]; u1.wd[2] = C[6]; u1.wd[3] = C[7];
      pb[2] = u0.v; pb[3] = u1.v;
    }

    // ---- O^T += V^T . P^T ----
    __builtin_amdgcn_s_setprio(1);
#pragma unroll
    for (int ks = 0; ks < 4; ++ks) {
      const us8 vf0 = *(const us8*)(vb0 + (koff0 ^ (ks << 5)));
      const us8 vf1 = *(const us8*)(vb0 + (koff1 ^ (ks << 5)));
      o0 = mfma32(vf0, pb[ks], o0);
      o1 = mfma32(vf1, pb[ks], o1);
    }
    __builtin_amdgcn_s_setprio(0);

    __syncthreads();   // next-tile staging drained; all done reading cur
  }

  // ---- epilogue: unnormalized O (f16) + l ----
  unsigned short* opq = (quarter == 0) ? Op0 : (quarter == 1) ? Op1
                       : (quarter == 2) ? Op2 : Op3;
  unsigned short* op = opq + (bhS + qrow) * HDD;
#pragma unroll
  for (int g = 0; g < 4; ++g) {
    ushort4 v0, v1;
#pragma unroll
    for (int j = 0; j < 4; ++j) {
      ((unsigned short*)&v0)[j] = f2h(o0[g * 4 + j]);
      ((unsigned short*)&v1)[j] = f2h(o1[g * 4 + j]);
    }
    *(ushort4*)&op[g * 8 + hi * 4]      = v0;
    *(ushort4*)&op[32 + g * 8 + hi * 4] = v1;
  }
  if (hi == 0)
    Ls[((size_t)quarter * 32 + bh) * SS + qrow] = lrun;
#undef STAGE
}

// ---------------------------------------------------------------------------
// Kernel 2b: combine 4 split-K parts -> packed f16 ctx (out_gemm A order).
// Same implicit max in all parts: out = (O0+O1+O2+O3)/(l0+l1+l2+l3).
// ---------------------------------------------------------------------------
__global__ __launch_bounds__(256)
void combine_kernel(const unsigned short* __restrict__ Op0,
                    const unsigned short* __restrict__ Op1,
                    const unsigned short* __restrict__ Op2,
                    const unsigned short* __restrict__ Op3,
                    const float* __restrict__ Ls,
                    unsigned short* __restrict__ Ch) {
  const int gid = blockIdx.x * 256 + threadIdx.x;
  const int row = gid >> 2, qtr = gid & 3;     // row 0..65535, 16 cols each
  const int bh = row >> 11, s = row & 2047;
  const int bi = bh >> 4, h = bh & 15;

  const float tot = (Ls[row] + Ls[65536 + row]) +
                    (Ls[131072 + row] + Ls[196608 + row]);
  const float rinv = 1.0f / tot;

  const int d0 = qtr * 16;
  const us8* p0 = (const us8*)&Op0[(size_t)row * HDD + d0];
  const us8* p1 = (const us8*)&Op1[(size_t)row * HDD + d0];
  const us8* p2 = (const us8*)&Op2[(size_t)row * HDD + d0];
  const us8* p3 = (const us8*)&Op3[(size_t)row * HDD + d0];
  const us8 a0 = p0[0], a1 = p0[1];
  const us8 b0 = p1[0], b1 = p1[1];
  const us8 c0 = p2[0], c1 = p2[1];
  const us8 d0v = p3[0], d1 = p3[1];

  const int mrow = bi * SS + s;
  const int mt = mrow >> 7, r = mrow & 127;
#pragma unroll
  for (int j4 = 0; j4 < 4; ++j4) {
    const int col = h * 64 + d0 + j4 * 4;
    const int kt2 = col >> 5, lg2 = (col >> 3) & 3, e0 = col & 7;
    const size_t off = (((size_t)(mt * 32 + kt2)) << 12) + fragoff(lg2, r) + e0;
    ushort4 hv;
#pragma unroll
    for (int j = 0; j < 4; ++j) {
      const int k = j4 * 4 + j;
      const float va = h2f(k < 8 ? a0[k] : a1[k - 8]);
      const float vb = h2f(k < 8 ? b0[k] : b1[k - 8]);
      const float vc = h2f(k < 8 ? c0[k] : c1[k - 8]);
      const float vd = h2f(k < 8 ? d0v[k] : d1[k - 8]);
      ((unsigned short*)&hv)[j] = f2h(((va + vb) + (vc + vd)) * rinv);
    }
    *(ushort4*)&Ch[off] = hv;
  }
}

// ---------------------------------------------------------------------------
// Kernel 3: output projection, double-buffered prefetch, fp32 out + bias.
// ---------------------------------------------------------------------------
__global__ __launch_bounds__(256, 3)
void out_gemm_kernel(const unsigned short* __restrict__ Ah_,
                     const unsigned short* __restrict__ Bh_,
                     const float* __restrict__ bo, float* __restrict__ out) {
  __shared__ __align__(16) unsigned short tiles[2][2][4096];
  const int tid = threadIdx.x, lane = tid & 63, wid = tid >> 6;
  const int l16 = lane & 15, lg = lane >> 4;
  const int wr = wid >> 1, wc = wid & 1;
  const int mt0 = blockIdx.y, nt0 = blockIdx.x;

  const unsigned short* gA = Ah_ + (((size_t)mt0 * 32) << 12);
  const unsigned short* gB = Bh_ + (((size_t)nt0 * 32) << 12);

#define GSTAGE(buf, kt_)                                                       \
  {                                                                            \
    const size_t ko_ = ((size_t)(kt_)) << 12;                                  \
    _Pragma("unroll")                                                          \
    for (int it_ = 0; it_ < 2; ++it_) {                                        \
      const int c_ = it_ * 256 + tid;                                          \
      gload16(gA + ko_ + c_ * 8, (char*)&tiles[buf][0][0] + c_ * 16);          \
      gload16(gB + ko_ + c_ * 8, (char*)&tiles[buf][1][0] + c_ * 16);          \
    }                                                                          \
  }

  f32x4 acc[4][4] = {};
  GSTAGE(0, 0)
  __syncthreads();
  for (int kt = 0; kt < 32; ++kt) {
    const int buf = kt & 1;
    if (kt + 1 < 32) GSTAGE(buf ^ 1, kt + 1)

    us8 a[4], b[4];
#pragma unroll
    for (int t = 0; t < 4; ++t) {
      a[t] = *(const us8*)&tiles[buf][0][fragoff(lg, wr * 64 + t * 16 + l16)];
      b[t] = *(const us8*)&tiles[buf][1][fragoff(lg, wc * 64 + t * 16 + l16)];
    }
#pragma unroll
    for (int mt = 0; mt < 4; ++mt)
#pragma unroll
      for (int nt = 0; nt < 4; ++nt)
        acc[mt][nt] = mfma16(a[mt], b[nt], acc[mt][nt]);
    __syncthreads();
  }
#undef GSTAGE

  const int m0 = mt0 * 128, n0 = nt0 * 128;
#pragma unroll
  for (int nt = 0; nt < 4; ++nt) {
    const int col = n0 + wc * 64 + nt * 16 + l16;
    const float bias = bo[col];
#pragma unroll
    for (int mt = 0; mt < 4; ++mt)
#pragma unroll
      for (int reg = 0; reg < 4; ++reg) {
        const int row = m0 + wr * 64 + mt * 16 + lg * 4 + reg;
        out[(size_t)row * HH + col] = acc[mt][nt][reg] + bias;
      }
  }
}

// ---------------------------------------------------------------------------
extern "C" void kernel_launch(void* const* d_in, const int* in_sizes, int n_in,
                              void* d_out, int out_size, void* d_ws, size_t ws_size,
                              hipStream_t stream) {
  const float* X    = (const float*)d_in[0];
  const float* mask = (const float*)d_in[1];
  const float* Wq   = (const float*)d_in[2];
  const float* bq   = (const float*)d_in[3];
  const float* Wk   = (const float*)d_in[4];
  const float* bk   = (const float*)d_in[5];
  const float* Wv   = (const float*)d_in[6];
  const float* bv   = (const float*)d_in[7];
  const float* Wo   = (const float*)d_in[8];
  const float* bo   = (const float*)d_in[9];
  float* out = (float*)d_out;

  unsigned char* w = (unsigned char*)d_ws;
  const size_t MB = 1024 * 1024;
  // layout (time-multiplexed aliases):
  //  0- 8: Xh (qkv A)        -> Op2 (attn quarter 2)
  //  8-16: Bh (qkv B, 6MB)   -> Op3 (attn quarter 3)
  // 16-24: qb
  // 24-32: kb                -> Ch (combine output)
  // 32-40: vt
  // 40-48: Op0   48-56: Op1
  // 56-58: Oh (Wo packed)    58-59: Ls    59+: maskl
  unsigned short* Xh  = (unsigned short*)(w);
  unsigned short* Bh  = (unsigned short*)(w + 8 * MB);
  unsigned short* qb  = (unsigned short*)(w + 16 * MB);
  unsigned short* kb  = (unsigned short*)(w + 24 * MB);
  unsigned short* vt  = (unsigned short*)(w + 32 * MB);
  unsigned short* Op0 = (unsigned short*)(w + 40 * MB);
  unsigned short* Op1 = (unsigned short*)(w + 48 * MB);
  unsigned short* Op2 = Xh;
  unsigned short* Op3 = Bh;
  unsigned short* Oh  = (unsigned short*)(w + 56 * MB);
  float*          Ls  = (float*)(w + 58 * MB);
  float*       maskl  = (float*)(w + 59 * MB);
  unsigned short* Ch  = kb;   // combine output over dead K buffer

  pack_kernel<<<2049, 256, 0, stream>>>(X, Wq, Wk, Wv, Wo, mask,
                                        Xh, Bh, Oh, maskl);
  qkv_gemm_kernel<<<dim3(24, 32), 256, 0, stream>>>(Xh, Bh, bq, bk, bv,
                                                    qb, kb, vt);
  attn_kernel<<<dim3(32, 32), 512, 0, stream>>>(qb, kb, vt, maskl,
                                                Op0, Op1, Op2, Op3, Ls);
  combine_kernel<<<1024, 256, 0, stream>>>(Op0, Op1, Op2, Op3, Ls, Ch);
  out_gemm_kernel<<<dim3(8, 32), 256, 0, stream>>>(Ch, Oh, bo, out);
}